// Round 7
// baseline (612.880 us; speedup 1.0000x reference)
//
#include <hip/hip_runtime.h>
#include <stdint.h>

typedef short bf16x8 __attribute__((ext_vector_type(8)));
typedef float f32x4 __attribute__((ext_vector_type(4)));

#define NTOK 4096   // B*T
#define DDIM 1024
#define FDIM 4096
#define NEXP 8
#define SEQ  2048

// fallback (64-pad) geometry
#define FB_MAXROWS 8704
#define FB_MAXTILES 136
// main (256-pad) geometry
#define G_MAXROWS 10240
#define G_MT 40

#define GLOAD16(g, l) __builtin_amdgcn_global_load_lds( \
    (const __attribute__((address_space(1))) unsigned int*)(const void*)(g), \
    (__attribute__((address_space(3))) unsigned int*)(l), 16, 0, 0)

#define WAIT_LGKM0() asm volatile("s_waitcnt lgkmcnt(0)" ::: "memory")
#define WAIT_VM4()   asm volatile("s_waitcnt vmcnt(4)" ::: "memory")
#define WAIT_VM0()   asm volatile("s_waitcnt vmcnt(0)" ::: "memory")
#define SBAR()       __builtin_amdgcn_s_barrier()
#define SCHEDB()     __builtin_amdgcn_sched_barrier(0)

__device__ __forceinline__ unsigned short f2bf(float f) {
    union { float f; unsigned int u; } v; v.f = f;
    unsigned int u = v.u;
    unsigned int r = (u + 0x7FFFu + ((u >> 16) & 1u)) >> 16;  // RNE
    return (unsigned short)r;
}
__device__ __forceinline__ unsigned int pk2(float a, float b) {
    return (unsigned int)f2bf(a) | ((unsigned int)f2bf(b) << 16);
}

// ---------------- fp32 -> bf16 streaming convert ----------------
__global__ __launch_bounds__(256) void cvt_kernel(
    const float* __restrict__ src, unsigned short* __restrict__ dst, int n4)
{
    int i = blockIdx.x * 256 + threadIdx.x;
    const int stride = gridDim.x * 256;
    for (; i < n4; i += stride) {
        const float4 v = ((const float4*)src)[i];
        ushort4 o;
        o.x = f2bf(v.x); o.y = f2bf(v.y); o.z = f2bf(v.z); o.w = f2bf(v.w);
        ((ushort4*)dst)[i] = o;
    }
}

// ---------------- Router: scores (fp32), top-2, counts ----------------
__global__ __launch_bounds__(256) void router_kernel(
    const float* __restrict__ x, const float* __restrict__ Wr,
    float* __restrict__ topk_vals, int* __restrict__ topk_idx,
    int* __restrict__ counts)
{
    const int wave = threadIdx.x >> 6;
    const int lane = threadIdx.x & 63;
    const int t = blockIdx.x * 4 + wave;
    const float4* xr = (const float4*)(x + (size_t)t * DDIM);

    float acc[NEXP];
#pragma unroll
    for (int e = 0; e < NEXP; ++e) acc[e] = 0.0f;

    for (int d = lane; d < DDIM / 4; d += 64) {
        const float4 xv = xr[d];
#pragma unroll
        for (int e = 0; e < NEXP; ++e) {
            const float4 wv = ((const float4*)(Wr + e * DDIM))[d];
            acc[e] = fmaf(xv.x, wv.x, acc[e]);
            acc[e] = fmaf(xv.y, wv.y, acc[e]);
            acc[e] = fmaf(xv.z, wv.z, acc[e]);
            acc[e] = fmaf(xv.w, wv.w, acc[e]);
        }
    }
#pragma unroll
    for (int e = 0; e < NEXP; ++e) {
        for (int off = 32; off > 0; off >>= 1)
            acc[e] += __shfl_xor(acc[e], off, 64);
    }
    if (lane == 0) {
        float best = -3.4e38f, second = -3.4e38f;
        int bi = 0, si = 0;
#pragma unroll
        for (int e = 0; e < NEXP; ++e) {
            const float s = acc[e];
            if (s > best) { second = best; si = bi; best = s; bi = e; }
            else if (s > second) { second = s; si = e; }
        }
        topk_vals[t * 2 + 0] = best;
        topk_vals[t * 2 + 1] = second;
        topk_idx[t * 2 + 0] = bi;
        topk_idx[t * 2 + 1] = si;
        atomicAdd(&counts[bi], 1);
        atomicAdd(&counts[si], 1);
    }
}

// ------------- softmax over sequence dim, per (batch, slot) -------------
__global__ __launch_bounds__(256) void softmax_seq_kernel(
    const float* __restrict__ tv, float* __restrict__ weight)
{
    const int b = blockIdx.x >> 1;
    const int k = blockIdx.x & 1;
    const float* base = tv + (size_t)b * SEQ * 2 + k;
    float* wbase = weight + (size_t)b * SEQ * 2 + k;
    __shared__ float red[256];
    const int tid = threadIdx.x;

    float m = -3.4e38f;
    for (int t = tid; t < SEQ; t += 256) m = fmaxf(m, base[t * 2]);
    red[tid] = m; __syncthreads();
    for (int s = 128; s > 0; s >>= 1) {
        if (tid < s) red[tid] = fmaxf(red[tid], red[tid + s]);
        __syncthreads();
    }
    m = red[0];
    __syncthreads();

    float sum = 0.0f;
    for (int t = tid; t < SEQ; t += 256) sum += expf(base[t * 2] - m);
    red[tid] = sum; __syncthreads();
    for (int s = 128; s > 0; s >>= 1) {
        if (tid < s) red[tid] += red[tid + s];
        __syncthreads();
    }
    const float inv = 1.0f / red[0];
    for (int t = tid; t < SEQ; t += 256)
        wbase[t * 2] = expf(base[t * 2] - m) * inv;
}

// ----- scan: pad expert segments to (1<<padBits)-row tiles; zero cursors -----
__global__ void scan_kernel(const int* __restrict__ counts,
                            int* __restrict__ padOff, int* __restrict__ cursor,
                            int padBits)
{
    if (threadIdx.x == 0) {
        const int pad = (1 << padBits) - 1;
        int o = 0;
        for (int e = 0; e < NEXP; ++e) {
            padOff[e] = o;
            o += ((counts[e] + pad) >> padBits) << padBits;
        }
        padOff[NEXP] = o;
    }
    if (threadIdx.x < NEXP) cursor[threadIdx.x] = 0;
}

// ----- scatter token-slot pairs into expert-sorted perm -----
__global__ __launch_bounds__(256) void scatter_kernel(
    const int* __restrict__ topk_idx, const int* __restrict__ padOff,
    int* __restrict__ cursor, int* __restrict__ perm)
{
    const int t = blockIdx.x * 256 + threadIdx.x;
#pragma unroll
    for (int k = 0; k < 2; ++k) {
        const int e = topk_idx[t * 2 + k];
        const int pos = padOff[e] + atomicAdd(&cursor[e], 1);
        perm[pos] = t * 2 + k;
    }
}

// ======== MAIN PATH: 256x256 tile, BK=32, 8 waves, 64KB LDS, counted-vmcnt pipe ========
// LDS chunk swizzle (both sides): LDS row slot (row, chunk c of 16B) holds global chunk
// c ^ (row&3). Stager pre-swizzles the global source; reader XORs the chunk index.
// Pipeline per K-tile t: ds_read(buf[t&1]) -> lgkm0 -> barrier -> stage t+2 into buf[t&1]
// -> 32 MFMA -> vmcnt(4) (t+1 landed, t+2 in flight) -> barrier.  [r4-proven schedule]

// GEMM1: h = relu(Xg @ W1b[e]^T + b1[e]); K=1024, NT=32. grid 640 = 16 col x 40 row.
__global__ __launch_bounds__(512, 2) void gemm1_g(
    const unsigned short* __restrict__ Xb, const unsigned short* __restrict__ Wb,
    const float* __restrict__ b1, const int* __restrict__ perm,
    const int* __restrict__ padOff, unsigned short* __restrict__ h)
{
    const int bid = blockIdx.x;                 // 640 = 8*80 -> bijective XCD swizzle
    const int swz = (bid & 7) * 80 + (bid >> 3);
    const int by = swz % G_MT;                  // row tile fastest (B col-panel L2-hot per XCD)
    const int bx = swz / G_MT;                  // 0..15
    const int row0 = by * 256;
    if (row0 >= padOff[NEXP]) return;
    int e = 0;
#pragma unroll
    for (int i = 1; i < NEXP; ++i) if (row0 >= padOff[i]) e = i;

    __shared__ unsigned short As[2][256 * 32];  // 2 x 16KB
    __shared__ unsigned short Bs[2][256 * 32];  // 2 x 16KB  -> 64KB total

    const int tid = threadIdx.x;
    const int w = tid >> 6, lane = tid & 63;
    const int wr = (w >> 2) * 128;              // 2 M-groups of waves
    const int wc = (w & 3) * 64;                // 4 N-groups
    const int fr = lane & 15, kg = lane >> 4;
    const int col0 = bx * 256;

    // stager: thread covers rows {srow, srow+128}, 16B chunk (tid&3), source chunk XOR'd
    const int srow = tid >> 2;                  // 0..127
    const int gch = ((tid & 3) ^ (srow & 3)) * 8;  // elements (8 bf16 = 16B)
    const unsigned short* aS[2];
    const unsigned short* bS[2];
#pragma unroll
    for (int j = 0; j < 2; ++j) {
        const int r = j * 128 + srow;
        const int pm = perm[row0 + r];
        const int tok = (pm >= 0) ? (pm >> 1) : 0;   // pad rows read token 0 (discarded later)
        aS[j] = Xb + (size_t)tok * DDIM + gch;
        bS[j] = Wb + ((size_t)e * FDIM + col0 + r) * DDIM + gch;
    }

    f32x4 acc[8][4] = {};

#define STG1(buf, koff) do { _Pragma("unroll") \
    for (int j = 0; j < 2; ++j) { \
        GLOAD16(aS[j] + (koff), &As[buf][(j * 512 + tid) * 8]); \
        GLOAD16(bS[j] + (koff), &Bs[buf][(j * 512 + tid) * 8]); \
    } } while (0)

    const int NT = DDIM / 32;   // 32
    STG1(0, 0);
    STG1(1, 32);
    SCHEDB(); WAIT_VM4(); SBAR(); SCHEDB();

    for (int t = 0; t < NT; ++t) {
        const int cur = t & 1;
        bf16x8 a[8], b[4];
        const int rch = (kg ^ (fr & 3)) << 3;   // swizzled chunk (shorts) for reader
#pragma unroll
        for (int m = 0; m < 8; ++m)
            a[m] = *(const bf16x8*)&As[cur][(wr + m * 16 + fr) * 32 + rch];
#pragma unroll
        for (int n = 0; n < 4; ++n)
            b[n] = *(const bf16x8*)&Bs[cur][(wc + n * 16 + fr) * 32 + rch];
        WAIT_LGKM0(); SCHEDB();
        SBAR(); SCHEDB();                       // all waves done reading buf[cur]
        if (t + 2 < NT) STG1(cur, (t + 2) * 32);
#pragma unroll
        for (int m = 0; m < 8; ++m)
#pragma unroll
            for (int n = 0; n < 4; ++n)
                acc[m][n] = __builtin_amdgcn_mfma_f32_16x16x32_bf16(a[m], b[n], acc[m][n], 0, 0, 0);
        SCHEDB();
        if (t + 2 < NT) { WAIT_VM4(); } else { WAIT_VM0(); }
        SBAR(); SCHEDB();                       // tile t+1 landed for all waves
    }
#undef STG1

#pragma unroll
    for (int n = 0; n < 4; ++n) {
        const int colg = col0 + wc + n * 16 + fr;
        const float bias = b1[e * FDIM + colg];
#pragma unroll
        for (int m = 0; m < 8; ++m) {
#pragma unroll
            for (int r = 0; r < 4; ++r) {
                const int rowg = row0 + wr + m * 16 + kg * 4 + r;
                h[(size_t)rowg * FDIM + colg] = f2bf(fmaxf(acc[m][n][r] + bias, 0.0f));
            }
        }
    }
}

// GEMM2: out[token] += weight * (h @ W2b[e]^T + b2[e]); split-K x2 (chunks of 2048, NT=64).
// grid 320 = (4 col x 2 kc) x 40 row.
__global__ __launch_bounds__(512, 2) void gemm2_g(
    const unsigned short* __restrict__ h, const unsigned short* __restrict__ Wb,
    const float* __restrict__ b2, const int* __restrict__ perm,
    const int* __restrict__ padOff, const float* __restrict__ weight,
    float* __restrict__ out)
{
    const int bid = blockIdx.x;                 // 320 = 8*40
    const int swz = (bid & 7) * 40 + (bid >> 3);
    const int by = swz % G_MT;
    const int rest = swz / G_MT;                // 0..7
    const int bx = rest & 3;
    const int kc = rest >> 2;                   // 0/1
    const int row0 = by * 256;
    if (row0 >= padOff[NEXP]) return;
    int e = 0;
#pragma unroll
    for (int i = 1; i < NEXP; ++i) if (row0 >= padOff[i]) e = i;

    __shared__ unsigned short As[2][256 * 32];
    __shared__ unsigned short Bs[2][256 * 32];

    const int tid = threadIdx.x;
    const int w = tid >> 6, lane = tid & 63;
    const int wr = (w >> 2) * 128;
    const int wc = (w & 3) * 64;
    const int fr = lane & 15, kg = lane >> 4;
    const int col0 = bx * 256;
    const int kbase = kc * (FDIM / 2);

    const int srow = tid >> 2;
    const int gch = ((tid & 3) ^ (srow & 3)) * 8;
    const unsigned short* aS[2];
    const unsigned short* bS[2];
#pragma unroll
    for (int j = 0; j < 2; ++j) {
        const int r = j * 128 + srow;
        aS[j] = h + (size_t)(row0 + r) * FDIM + kbase + gch;
        bS[j] = Wb + ((size_t)e * DDIM + col0 + r) * FDIM + kbase + gch;
    }

    f32x4 acc[8][4] = {};

#define STG2(buf, koff) do { _Pragma("unroll") \
    for (int j = 0; j < 2; ++j) { \
        GLOAD16(aS[j] + (koff), &As[buf][(j * 512 + tid) * 8]); \
        GLOAD16(bS[j] + (koff), &Bs[buf][(j * 512 + tid) * 8]); \
    } } while (0)

    const int NT = (FDIM / 2) / 32;   // 64
    STG2(0, 0);
    STG2(1, 32);
    SCHEDB(); WAIT_VM4(); SBAR(); SCHEDB();

    for (int t = 0; t < NT; ++t) {
        const int cur = t & 1;
        bf16x8 a[8], b[4];
        const int rch = (kg ^ (fr & 3)) << 3;
#pragma unroll
        for (int m = 0; m < 8; ++m)
            a[m] = *(const bf16x8*)&As[cur][(wr + m * 16 + fr) * 32 + rch];
#pragma unroll
        for (int n = 0; n < 4; ++n)
            b[n] = *(const bf16x8*)&Bs[cur][(wc + n * 16 + fr) * 32 + rch];
        WAIT_LGKM0(); SCHEDB();
        SBAR(); SCHEDB();
        if (t + 2 < NT) STG2(cur, (t + 2) * 32);
#pragma unroll
        for (int m = 0; m < 8; ++m)
#pragma unroll
            for (int n = 0; n < 4; ++n)
                acc[m][n] = __builtin_amdgcn_mfma_f32_16x16x32_bf16(a[m], b[n], acc[m][n], 0, 0, 0);
        SCHEDB();
        if (t + 2 < NT) { WAIT_VM4(); } else { WAIT_VM0(); }
        SBAR(); SCHEDB();
    }
#undef STG2

#pragma unroll
    for (int n = 0; n < 4; ++n) {
        const int colg = col0 + wc + n * 16 + fr;
        const float bias = (kc == 0) ? b2[e * DDIM + colg] : 0.0f;
#pragma unroll
        for (int m = 0; m < 8; ++m) {
#pragma unroll
            for (int r = 0; r < 4; ++r) {
                const int rowg = row0 + wr + m * 16 + kg * 4 + r;
                const int pm = perm[rowg];
                if (pm >= 0) {
                    const float wgt = weight[pm];
                    atomicAdd(&out[(size_t)(pm >> 1) * DDIM + colg], (acc[m][n][r] + bias) * wgt);
                }
            }
        }
    }
}

// =================== FALLBACK PATH (round-1 64x64 kernels) ===================

__global__ __launch_bounds__(256) void gemm1_fb(
    const float* __restrict__ x, const float* __restrict__ W1,
    const float* __restrict__ b1, const int* __restrict__ perm,
    const int* __restrict__ padOff, unsigned short* __restrict__ h)
{
    const int row0 = blockIdx.y * 64;
    if (row0 >= padOff[NEXP]) return;
    int e = 0;
#pragma unroll
    for (int i = 1; i < NEXP; ++i) if (row0 >= padOff[i]) e = i;

    __shared__ unsigned short As[64][40];
    __shared__ unsigned short Bs[64][40];

    const int tid = threadIdx.x;
    const int srow = tid >> 2;
    const int skp = (tid & 3) << 3;

    const int pm = perm[row0 + srow];
    const float* aSrc = (pm >= 0) ? (x + (size_t)(pm >> 1) * DDIM + skp) : 0;
    const int fRow = blockIdx.x * 64 + srow;
    const float* bSrc = W1 + ((size_t)e * FDIM + fRow) * DDIM + skp;

    const int lane = tid & 63;
    const int wm = ((tid >> 7) & 1) * 32;
    const int wn = ((tid >> 6) & 1) * 32;
    const int fr = lane & 15;
    const int kg = lane >> 4;

    f32x4 acc[2][2] = {{{0,0,0,0},{0,0,0,0}},{{0,0,0,0},{0,0,0,0}}};

    for (int k0 = 0; k0 < DDIM; k0 += 32) {
        uint4 av = make_uint4(0, 0, 0, 0);
        if (aSrc) {
            const float4 lo = *(const float4*)(aSrc + k0);
            const float4 hi = *(const float4*)(aSrc + k0 + 4);
            av.x = pk2(lo.x, lo.y); av.y = pk2(lo.z, lo.w);
            av.z = pk2(hi.x, hi.y); av.w = pk2(hi.z, hi.w);
        }
        const float4 bl = *(const float4*)(bSrc + k0);
        const float4 bh = *(const float4*)(bSrc + k0 + 4);
        uint4 bv;
        bv.x = pk2(bl.x, bl.y); bv.y = pk2(bl.z, bl.w);
        bv.z = pk2(bh.x, bh.y); bv.w = pk2(bh.z, bh.w);

        __syncthreads();
        *(uint4*)&As[srow][skp] = av;
        *(uint4*)&Bs[srow][skp] = bv;
        __syncthreads();

        const bf16x8 a0 = *(const bf16x8*)&As[wm + 0  + fr][kg << 3];
        const bf16x8 a1 = *(const bf16x8*)&As[wm + 16 + fr][kg << 3];
        const bf16x8 b0 = *(const bf16x8*)&Bs[wn + 0  + fr][kg << 3];
        const bf16x8 b1v = *(const bf16x8*)&Bs[wn + 16 + fr][kg << 3];
        acc[0][0] = __builtin_amdgcn_mfma_f32_16x16x32_bf16(a0, b0,  acc[0][0], 0, 0, 0);
        acc[0][1] = __builtin_amdgcn_mfma_f32_16x16x32_bf16(a0, b1v, acc[0][1], 0, 0, 0);
        acc[1][0] = __builtin_amdgcn_mfma_f32_16x16x32_bf16(a1, b0,  acc[1][0], 0, 0, 0);
        acc[1][1] = __builtin_amdgcn_mfma_f32_16x16x32_bf16(a1, b1v, acc[1][1], 0, 0, 0);
    }

#pragma unroll
    for (int mi = 0; mi < 2; ++mi)
#pragma unroll
        for (int ni = 0; ni < 2; ++ni) {
            const int colg = blockIdx.x * 64 + wn + ni * 16 + fr;
            const float bias = b1[e * FDIM + colg];
#pragma unroll
            for (int r = 0; r < 4; ++r) {
                const int rowg = row0 + wm + mi * 16 + (kg << 2) + r;
                float v = acc[mi][ni][r] + bias;
                v = fmaxf(v, 0.0f);
                h[(size_t)rowg * FDIM + colg] = f2bf(v);
            }
        }
}

__global__ __launch_bounds__(256) void gemm2_fb(
    const unsigned short* __restrict__ h, const float* __restrict__ W2,
    const float* __restrict__ b2, const int* __restrict__ perm,
    const int* __restrict__ padOff, const float* __restrict__ weight,
    float* __restrict__ out)
{
    const int row0 = blockIdx.y * 64;
    if (row0 >= padOff[NEXP]) return;
    int e = 0;
#pragma unroll
    for (int i = 1; i < NEXP; ++i) if (row0 >= padOff[i]) e = i;

    __shared__ unsigned short As[64][40];
    __shared__ unsigned short Bs[64][40];

    const int tid = threadIdx.x;
    const int srow = tid >> 2;
    const int skp = (tid & 3) << 3;

    const unsigned short* aSrc = h + (size_t)(row0 + srow) * FDIM + skp;
    const int dRow = blockIdx.x * 64 + srow;
    const float* bSrc = W2 + ((size_t)e * DDIM + dRow) * FDIM + skp;

    const int lane = tid & 63;
    const int wm = ((tid >> 7) & 1) * 32;
    const int wn = ((tid >> 6) & 1) * 32;
    const int fr = lane & 15;
    const int kg = lane >> 4;

    f32x4 acc[2][2] = {{{0,0,0,0},{0,0,0,0}},{{0,0,0,0},{0,0,0,0}}};

    for (int k0 = 0; k0 < FDIM; k0 += 32) {
        const uint4 av = *(const uint4*)(aSrc + k0);
        const float4 bl = *(const float4*)(bSrc + k0);
        const float4 bh = *(const float4*)(bSrc + k0 + 4);
        uint4 bv;
        bv.x = pk2(bl.x, bl.y); bv.y = pk2(bl.z, bl.w);
        bv.z = pk2(bh.x, bh.y); bv.w = pk2(bh.z, bh.w);

        __syncthreads();
        *(uint4*)&As[srow][skp] = av;
        *(uint4*)&Bs[srow][skp] = bv;
        __syncthreads();

        const bf16x8 a0 = *(const bf16x8*)&As[wm + 0  + fr][kg << 3];
        const bf16x8 a1 = *(const bf16x8*)&As[wm + 16 + fr][kg << 3];
        const bf16x8 b0 = *(const bf16x8*)&Bs[wn + 0  + fr][kg << 3];
        const bf16x8 b1v = *(const bf16x8*)&Bs[wn + 16 + fr][kg << 3];
        acc[0][0] = __builtin_amdgcn_mfma_f32_16x16x32_bf16(a0, b0,  acc[0][0], 0, 0, 0);
        acc[0][1] = __builtin_amdgcn_mfma_f32_16x16x32_bf16(a0, b1v, acc[0][1], 0, 0, 0);
        acc[1][0] = __builtin_amdgcn_mfma_f32_16x16x32_bf16(a1, b0,  acc[1][0], 0, 0, 0);
        acc[1][1] = __builtin_amdgcn_mfma_f32_16x16x32_bf16(a1, b1v, acc[1][1], 0, 0, 0);
    }

#pragma unroll
    for (int mi = 0; mi < 2; ++mi)
#pragma unroll
        for (int ni = 0; ni < 2; ++ni) {
            const int colg = blockIdx.x * 64 + wn + ni * 16 + fr;
            const float bias = b2[e * DDIM + colg];
#pragma unroll
            for (int r = 0; r < 4; ++r) {
                const int rowg = row0 + wm + mi * 16 + (kg << 2) + r;
                const int pm = perm[rowg];
                if (pm >= 0) {
                    const float w = weight[pm];
                    const float v = (acc[mi][ni][r] + bias) * w;
                    atomicAdd(&out[(size_t)(pm >> 1) * DDIM + colg], v);
                }
            }
        }
}

extern "C" void kernel_launch(void* const* d_in, const int* in_sizes, int n_in,
                              void* d_out, int out_size, void* d_ws, size_t ws_size,
                              hipStream_t stream)
{
    const float* x  = (const float*)d_in[0];
    const float* Wr = (const float*)d_in[1];
    const float* W1 = (const float*)d_in[2];
    const float* b1 = (const float*)d_in[3];
    const float* W2 = (const float*)d_in[4];
    const float* b2 = (const float*)d_in[5];
    float* out = (float*)d_out;
    char* ws = (char*)d_ws;

    float* topk_vals = (float*)(ws);                  // 32KB
    float* weight    = (float*)(ws + 32768);          // 32KB
    int*   topk_idx  = (int*)(ws + 65536);            // 32KB
    int*   counts    = (int*)(ws + 98304);
    int*   padOff    = (int*)(ws + 98368);
    int*   cursor    = (int*)(ws + 98432);
    int*   perm      = (int*)(ws + 98496);            // 10240 ints -> ends 139456

    // r5 ran with this exact 159.6MB layout -> ws_size >= 159645696 is proven available
    const size_t NEED = 159645696ULL;

    if (ws_size >= NEED) {
        unsigned short* Xb = (unsigned short*)(ws + 262144);     // 8.39 MB
        unsigned short* h  = (unsigned short*)(ws + 8650752);    // 10240*4096*2 = 83.9 MB
        unsigned short* Wb = (unsigned short*)(ws + 92536832);   // 67.1 MB -> ends 159645696

        hipMemsetAsync(counts, 0, NEXP * sizeof(int), stream);
        hipMemsetAsync(perm, 0xFF, G_MAXROWS * sizeof(int), stream);
        hipMemsetAsync(out, 0, (size_t)out_size * sizeof(float), stream);

        cvt_kernel<<<2048, 256, 0, stream>>>(x, Xb, NTOK * DDIM / 4);
        cvt_kernel<<<2048, 256, 0, stream>>>(W1, Wb, NEXP * FDIM * DDIM / 4);
        router_kernel<<<NTOK / 4, 256, 0, stream>>>(x, Wr, topk_vals, topk_idx, counts);
        softmax_seq_kernel<<<4, 256, 0, stream>>>(topk_vals, weight);
        scan_kernel<<<1, 64, 0, stream>>>(counts, padOff, cursor, 8);
        scatter_kernel<<<NTOK / 256, 256, 0, stream>>>(topk_idx, padOff, cursor, perm);

        gemm1_g<<<16 * G_MT, 512, 0, stream>>>(Xb, Wb, b1, perm, padOff, h);
        // W2 conversion reuses Wb (stream-ordered after gemm1 finished with W1b)
        cvt_kernel<<<2048, 256, 0, stream>>>(W2, Wb, NEXP * DDIM * FDIM / 4);
        gemm2_g<<<8 * G_MT, 512, 0, stream>>>(h, Wb, b2, perm, padOff, weight, out);
    } else {
        unsigned short* h = (unsigned short*)(ws + 172032);

        hipMemsetAsync(counts, 0, NEXP * sizeof(int), stream);
        hipMemsetAsync(perm, 0xFF, FB_MAXROWS * sizeof(int), stream);
        hipMemsetAsync(out, 0, (size_t)out_size * sizeof(float), stream);

        router_kernel<<<NTOK / 4, 256, 0, stream>>>(x, Wr, topk_vals, topk_idx, counts);
        softmax_seq_kernel<<<4, 256, 0, stream>>>(topk_vals, weight);
        scan_kernel<<<1, 64, 0, stream>>>(counts, padOff, cursor, 6);
        scatter_kernel<<<NTOK / 256, 256, 0, stream>>>(topk_idx, padOff, cursor, perm);

        gemm1_fb<<<dim3(FDIM / 64, FB_MAXTILES), 256, 0, stream>>>(x, W1, b1, perm, padOff, h);
        gemm2_fb<<<dim3(DDIM / 64, FB_MAXTILES), 256, 0, stream>>>(h, W2, b2, perm, padOff, weight, out);
    }
}

// Round 8
// 494.514 us; speedup vs baseline: 1.2394x; 1.2394x over previous
//
#include <hip/hip_runtime.h>
#include <stdint.h>

typedef short bf16x8 __attribute__((ext_vector_type(8)));
typedef float f32x4 __attribute__((ext_vector_type(4)));

#define NTOK 4096   // B*T
#define DDIM 1024
#define FDIM 4096
#define NEXP 8
#define SEQ  2048

// fallback (64-pad) geometry
#define FB_MAXROWS 8704
#define FB_MAXTILES 136
// main (128-pad) geometry
#define N_MAXROWS 9216
#define N_MT 72

#define GLOAD16(g, l) __builtin_amdgcn_global_load_lds( \
    (const __attribute__((address_space(1))) unsigned int*)(const void*)(g), \
    (__attribute__((address_space(3))) unsigned int*)(l), 16, 0, 0)

__device__ __forceinline__ unsigned short f2bf(float f) {
    union { float f; unsigned int u; } v; v.f = f;
    unsigned int u = v.u;
    unsigned int r = (u + 0x7FFFu + ((u >> 16) & 1u)) >> 16;  // RNE
    return (unsigned short)r;
}
__device__ __forceinline__ unsigned int pk2(float a, float b) {
    return (unsigned int)f2bf(a) | ((unsigned int)f2bf(b) << 16);
}

// ---------------- fp32 -> bf16 streaming convert ----------------
__global__ __launch_bounds__(256) void cvt_kernel(
    const float* __restrict__ src, unsigned short* __restrict__ dst, int n4)
{
    int i = blockIdx.x * 256 + threadIdx.x;
    const int stride = gridDim.x * 256;
    for (; i < n4; i += stride) {
        const float4 v = ((const float4*)src)[i];
        ushort4 o;
        o.x = f2bf(v.x); o.y = f2bf(v.y); o.z = f2bf(v.z); o.w = f2bf(v.w);
        ((ushort4*)dst)[i] = o;
    }
}

// ---------------- Router: scores (fp32), top-2, counts ----------------
__global__ __launch_bounds__(256) void router_kernel(
    const float* __restrict__ x, const float* __restrict__ Wr,
    float* __restrict__ topk_vals, int* __restrict__ topk_idx,
    int* __restrict__ counts)
{
    const int wave = threadIdx.x >> 6;
    const int lane = threadIdx.x & 63;
    const int t = blockIdx.x * 4 + wave;
    const float4* xr = (const float4*)(x + (size_t)t * DDIM);

    float acc[NEXP];
#pragma unroll
    for (int e = 0; e < NEXP; ++e) acc[e] = 0.0f;

    for (int d = lane; d < DDIM / 4; d += 64) {
        const float4 xv = xr[d];
#pragma unroll
        for (int e = 0; e < NEXP; ++e) {
            const float4 wv = ((const float4*)(Wr + e * DDIM))[d];
            acc[e] = fmaf(xv.x, wv.x, acc[e]);
            acc[e] = fmaf(xv.y, wv.y, acc[e]);
            acc[e] = fmaf(xv.z, wv.z, acc[e]);
            acc[e] = fmaf(xv.w, wv.w, acc[e]);
        }
    }
#pragma unroll
    for (int e = 0; e < NEXP; ++e) {
        for (int off = 32; off > 0; off >>= 1)
            acc[e] += __shfl_xor(acc[e], off, 64);
    }
    if (lane == 0) {
        float best = -3.4e38f, second = -3.4e38f;
        int bi = 0, si = 0;
#pragma unroll
        for (int e = 0; e < NEXP; ++e) {
            const float s = acc[e];
            if (s > best) { second = best; si = bi; best = s; bi = e; }
            else if (s > second) { second = s; si = e; }
        }
        topk_vals[t * 2 + 0] = best;
        topk_vals[t * 2 + 1] = second;
        topk_idx[t * 2 + 0] = bi;
        topk_idx[t * 2 + 1] = si;
        atomicAdd(&counts[bi], 1);
        atomicAdd(&counts[si], 1);
    }
}

// ------------- softmax over sequence dim, per (batch, slot) -------------
__global__ __launch_bounds__(256) void softmax_seq_kernel(
    const float* __restrict__ tv, float* __restrict__ weight)
{
    const int b = blockIdx.x >> 1;
    const int k = blockIdx.x & 1;
    const float* base = tv + (size_t)b * SEQ * 2 + k;
    float* wbase = weight + (size_t)b * SEQ * 2 + k;
    __shared__ float red[256];
    const int tid = threadIdx.x;

    float m = -3.4e38f;
    for (int t = tid; t < SEQ; t += 256) m = fmaxf(m, base[t * 2]);
    red[tid] = m; __syncthreads();
    for (int s = 128; s > 0; s >>= 1) {
        if (tid < s) red[tid] = fmaxf(red[tid], red[tid + s]);
        __syncthreads();
    }
    m = red[0];
    __syncthreads();

    float sum = 0.0f;
    for (int t = tid; t < SEQ; t += 256) sum += expf(base[t * 2] - m);
    red[tid] = sum; __syncthreads();
    for (int s = 128; s > 0; s >>= 1) {
        if (tid < s) red[tid] += red[tid + s];
        __syncthreads();
    }
    const float inv = 1.0f / red[0];
    for (int t = tid; t < SEQ; t += 256)
        wbase[t * 2] = expf(base[t * 2] - m) * inv;
}

// ----- scan: pad expert segments to (1<<padBits)-row tiles; zero cursors -----
__global__ void scan_kernel(const int* __restrict__ counts,
                            int* __restrict__ padOff, int* __restrict__ cursor,
                            int padBits)
{
    if (threadIdx.x == 0) {
        const int pad = (1 << padBits) - 1;
        int o = 0;
        for (int e = 0; e < NEXP; ++e) {
            padOff[e] = o;
            o += ((counts[e] + pad) >> padBits) << padBits;
        }
        padOff[NEXP] = o;
    }
    if (threadIdx.x < NEXP) cursor[threadIdx.x] = 0;
}

// ----- scatter token-slot pairs into expert-sorted perm -----
__global__ __launch_bounds__(256) void scatter_kernel(
    const int* __restrict__ topk_idx, const int* __restrict__ padOff,
    int* __restrict__ cursor, int* __restrict__ perm)
{
    const int t = blockIdx.x * 256 + threadIdx.x;
#pragma unroll
    for (int k = 0; k < 2; ++k) {
        const int e = topk_idx[t * 2 + k];
        const int pos = padOff[e] + atomicAdd(&cursor[e], 1);
        perm[pos] = t * 2 + k;
    }
}

// ======== MAIN PATH: 128x128, BK=64, SINGLE-buffered 32KB LDS, 4 blocks/CU ========
// m97 structure: stage -> sync -> ds_read+MFMA -> sync. Latency hidden by 4 resident
// blocks per CU (m114 inter-block overlap), NOT by in-kernel pipelining.
// XOR chunk swizzle (both sides, r4-proven 0-conflict): LDS slot (row, chunk c of 16B)
// holds global chunk c ^ (row&7); reader XORs with fr&7.

// GEMM1: h = relu(Xg @ W1b[e]^T + b1[e]); K=1024, NT=16. grid 2304 (32 col x 72 row).
__global__ __launch_bounds__(256, 4) void gemm1_s(
    const unsigned short* __restrict__ Xb, const unsigned short* __restrict__ Wb,
    const float* __restrict__ b1, const int* __restrict__ perm,
    const int* __restrict__ padOff, unsigned short* __restrict__ h)
{
    const int bid = blockIdx.x;                 // 2304 = 8*288 -> bijective XCD swizzle
    const int swz = (bid & 7) * 288 + (bid >> 3);
    const int by = swz % N_MT;                  // row tile fastest (B col-panel L2-hot per XCD)
    const int bx = swz / N_MT;                  // 0..31
    const int row0 = by * 128;
    if (row0 >= padOff[NEXP]) return;
    int e = 0;
#pragma unroll
    for (int i = 1; i < NEXP; ++i) if (row0 >= padOff[i]) e = i;

    __shared__ unsigned short As[128 * 64];     // 16KB
    __shared__ unsigned short Bs[128 * 64];     // 16KB -> 32KB total, 4-5 blocks/CU

    const int tid = threadIdx.x;
    const int w = tid >> 6, lane = tid & 63;
    const int wm = (w & 1) * 64, wn = (w >> 1) * 64;
    const int fr = lane & 15, kg = lane >> 4;
    const int col0 = bx * 128;

    // stager: glds dest is linear (base + lane*16B); source chunk pre-XOR'd by row&7
    const int gchunk = ((lane & 7) ^ (lane >> 3)) * 8;
    const unsigned short* aSrc[4];
    const unsigned short* bSrc[4];
#pragma unroll
    for (int j = 0; j < 4; ++j) {
        const int r = w * 32 + j * 8 + (lane >> 3);
        const int pm = perm[row0 + r];
        const int tok = (pm >= 0) ? (pm >> 1) : 0;   // pad rows read token 0 (discarded later)
        aSrc[j] = Xb + (size_t)tok * DDIM + gchunk;
        bSrc[j] = Wb + ((size_t)e * FDIM + col0 + r) * DDIM + gchunk;
    }

    f32x4 acc[4][4] = {};

    const int NT = DDIM / 64;   // 16
    for (int t = 0; t < NT; ++t) {
        const int koff = t * 64;
#pragma unroll
        for (int j = 0; j < 4; ++j) {
            GLOAD16(aSrc[j] + koff, &As[(w * 4 + j) * 512]);
            GLOAD16(bSrc[j] + koff, &Bs[(w * 4 + j) * 512]);
        }
        __syncthreads();   // vmcnt(0)+lgkm drain; filled by 3 sibling blocks on this CU
#pragma unroll
        for (int kk = 0; kk < 2; ++kk) {
            const int cx = (kk << 2) | kg;
            bf16x8 a[4], b[4];
#pragma unroll
            for (int m = 0; m < 4; ++m)
                a[m] = *(const bf16x8*)&As[(wm + m * 16 + fr) * 64 + ((cx ^ (fr & 7)) << 3)];
#pragma unroll
            for (int n = 0; n < 4; ++n)
                b[n] = *(const bf16x8*)&Bs[(wn + n * 16 + fr) * 64 + ((cx ^ (fr & 7)) << 3)];
#pragma unroll
            for (int m = 0; m < 4; ++m)
#pragma unroll
                for (int n = 0; n < 4; ++n)
                    acc[m][n] = __builtin_amdgcn_mfma_f32_16x16x32_bf16(a[m], b[n], acc[m][n], 0, 0, 0);
        }
        __syncthreads();   // reads done before next stage overwrites
    }

#pragma unroll
    for (int n = 0; n < 4; ++n) {
        const int colg = col0 + wn + n * 16 + fr;
        const float bias = b1[e * FDIM + colg];
#pragma unroll
        for (int m = 0; m < 4; ++m) {
#pragma unroll
            for (int r = 0; r < 4; ++r) {
                const int rowg = row0 + wm + m * 16 + kg * 4 + r;
                h[(size_t)rowg * FDIM + colg] = f2bf(fmaxf(acc[m][n][r] + bias, 0.0f));
            }
        }
    }
}

// GEMM2: out[token] += weight * (h @ W2b[e]^T + b2[e]); split-K x2 (chunks 2048, NT=32).
// grid 1152 (8 col x 2 kc x 72 row).
__global__ __launch_bounds__(256, 4) void gemm2_s(
    const unsigned short* __restrict__ h, const unsigned short* __restrict__ Wb,
    const float* __restrict__ b2, const int* __restrict__ perm,
    const int* __restrict__ padOff, const float* __restrict__ weight,
    float* __restrict__ out)
{
    const int bid = blockIdx.x;                 // 1152 = 8*144
    const int swz = (bid & 7) * 144 + (bid >> 3);
    const int by = swz % N_MT;                  // row tile fastest
    const int rest = swz / N_MT;                // 0..15
    const int bx = rest & 7;
    const int kc = rest >> 3;                   // 0/1
    const int row0 = by * 128;
    if (row0 >= padOff[NEXP]) return;
    int e = 0;
#pragma unroll
    for (int i = 1; i < NEXP; ++i) if (row0 >= padOff[i]) e = i;

    __shared__ unsigned short As[128 * 64];
    __shared__ unsigned short Bs[128 * 64];

    const int tid = threadIdx.x;
    const int w = tid >> 6, lane = tid & 63;
    const int wm = (w & 1) * 64, wn = (w >> 1) * 64;
    const int fr = lane & 15, kg = lane >> 4;
    const int col0 = bx * 128;
    const int kbase = kc * (FDIM / 2);

    const int gchunk = ((lane & 7) ^ (lane >> 3)) * 8;
    const unsigned short* aSrc[4];
    const unsigned short* bSrc[4];
#pragma unroll
    for (int j = 0; j < 4; ++j) {
        const int r = w * 32 + j * 8 + (lane >> 3);
        aSrc[j] = h + (size_t)(row0 + r) * FDIM + kbase + gchunk;
        bSrc[j] = Wb + ((size_t)e * DDIM + col0 + r) * FDIM + kbase + gchunk;
    }

    f32x4 acc[4][4] = {};

    const int NT = (FDIM / 2) / 64;   // 32
    for (int t = 0; t < NT; ++t) {
        const int koff = t * 64;
#pragma unroll
        for (int j = 0; j < 4; ++j) {
            GLOAD16(aSrc[j] + koff, &As[(w * 4 + j) * 512]);
            GLOAD16(bSrc[j] + koff, &Bs[(w * 4 + j) * 512]);
        }
        __syncthreads();
#pragma unroll
        for (int kk = 0; kk < 2; ++kk) {
            const int cx = (kk << 2) | kg;
            bf16x8 a[4], b[4];
#pragma unroll
            for (int m = 0; m < 4; ++m)
                a[m] = *(const bf16x8*)&As[(wm + m * 16 + fr) * 64 + ((cx ^ (fr & 7)) << 3)];
#pragma unroll
            for (int n = 0; n < 4; ++n)
                b[n] = *(const bf16x8*)&Bs[(wn + n * 16 + fr) * 64 + ((cx ^ (fr & 7)) << 3)];
#pragma unroll
            for (int m = 0; m < 4; ++m)
#pragma unroll
                for (int n = 0; n < 4; ++n)
                    acc[m][n] = __builtin_amdgcn_mfma_f32_16x16x32_bf16(a[m], b[n], acc[m][n], 0, 0, 0);
        }
        __syncthreads();
    }

#pragma unroll
    for (int n = 0; n < 4; ++n) {
        const int colg = col0 + wn + n * 16 + fr;
        const float bias = (kc == 0) ? b2[e * DDIM + colg] : 0.0f;
#pragma unroll
        for (int m = 0; m < 4; ++m) {
#pragma unroll
            for (int r = 0; r < 4; ++r) {
                const int rowg = row0 + wm + m * 16 + kg * 4 + r;
                const int pm = perm[rowg];
                if (pm >= 0) {
                    const float wgt = weight[pm];
                    atomicAdd(&out[(size_t)(pm >> 1) * DDIM + colg], (acc[m][n][r] + bias) * wgt);
                }
            }
        }
    }
}

// =================== FALLBACK PATH (round-1 64x64 kernels) ===================

__global__ __launch_bounds__(256) void gemm1_fb(
    const float* __restrict__ x, const float* __restrict__ W1,
    const float* __restrict__ b1, const int* __restrict__ perm,
    const int* __restrict__ padOff, unsigned short* __restrict__ h)
{
    const int row0 = blockIdx.y * 64;
    if (row0 >= padOff[NEXP]) return;
    int e = 0;
#pragma unroll
    for (int i = 1; i < NEXP; ++i) if (row0 >= padOff[i]) e = i;

    __shared__ unsigned short As[64][40];
    __shared__ unsigned short Bs[64][40];

    const int tid = threadIdx.x;
    const int srow = tid >> 2;
    const int skp = (tid & 3) << 3;

    const int pm = perm[row0 + srow];
    const float* aSrc = (pm >= 0) ? (x + (size_t)(pm >> 1) * DDIM + skp) : 0;
    const int fRow = blockIdx.x * 64 + srow;
    const float* bSrc = W1 + ((size_t)e * FDIM + fRow) * DDIM + skp;

    const int lane = tid & 63;
    const int wm = ((tid >> 7) & 1) * 32;
    const int wn = ((tid >> 6) & 1) * 32;
    const int fr = lane & 15;
    const int kg = lane >> 4;

    f32x4 acc[2][2] = {{{0,0,0,0},{0,0,0,0}},{{0,0,0,0},{0,0,0,0}}};

    for (int k0 = 0; k0 < DDIM; k0 += 32) {
        uint4 av = make_uint4(0, 0, 0, 0);
        if (aSrc) {
            const float4 lo = *(const float4*)(aSrc + k0);
            const float4 hi = *(const float4*)(aSrc + k0 + 4);
            av.x = pk2(lo.x, lo.y); av.y = pk2(lo.z, lo.w);
            av.z = pk2(hi.x, hi.y); av.w = pk2(hi.z, hi.w);
        }
        const float4 bl = *(const float4*)(bSrc + k0);
        const float4 bh = *(const float4*)(bSrc + k0 + 4);
        uint4 bv;
        bv.x = pk2(bl.x, bl.y); bv.y = pk2(bl.z, bl.w);
        bv.z = pk2(bh.x, bh.y); bv.w = pk2(bh.z, bh.w);

        __syncthreads();
        *(uint4*)&As[srow][skp] = av;
        *(uint4*)&Bs[srow][skp] = bv;
        __syncthreads();

        const bf16x8 a0 = *(const bf16x8*)&As[wm + 0  + fr][kg << 3];
        const bf16x8 a1 = *(const bf16x8*)&As[wm + 16 + fr][kg << 3];
        const bf16x8 b0 = *(const bf16x8*)&Bs[wn + 0  + fr][kg << 3];
        const bf16x8 b1v = *(const bf16x8*)&Bs[wn + 16 + fr][kg << 3];
        acc[0][0] = __builtin_amdgcn_mfma_f32_16x16x32_bf16(a0, b0,  acc[0][0], 0, 0, 0);
        acc[0][1] = __builtin_amdgcn_mfma_f32_16x16x32_bf16(a0, b1v, acc[0][1], 0, 0, 0);
        acc[1][0] = __builtin_amdgcn_mfma_f32_16x16x32_bf16(a1, b0,  acc[1][0], 0, 0, 0);
        acc[1][1] = __builtin_amdgcn_mfma_f32_16x16x32_bf16(a1, b1v, acc[1][1], 0, 0, 0);
    }

#pragma unroll
    for (int mi = 0; mi < 2; ++mi)
#pragma unroll
        for (int ni = 0; ni < 2; ++ni) {
            const int colg = blockIdx.x * 64 + wn + ni * 16 + fr;
            const float bias = b1[e * FDIM + colg];
#pragma unroll
            for (int r = 0; r < 4; ++r) {
                const int rowg = row0 + wm + mi * 16 + (kg << 2) + r;
                float v = acc[mi][ni][r] + bias;
                v = fmaxf(v, 0.0f);
                h[(size_t)rowg * FDIM + colg] = f2bf(v);
            }
        }
}

__global__ __launch_bounds__(256) void gemm2_fb(
    const unsigned short* __restrict__ h, const float* __restrict__ W2,
    const float* __restrict__ b2, const int* __restrict__ perm,
    const int* __restrict__ padOff, const float* __restrict__ weight,
    float* __restrict__ out)
{
    const int row0 = blockIdx.y * 64;
    if (row0 >= padOff[NEXP]) return;
    int e = 0;
#pragma unroll
    for (int i = 1; i < NEXP; ++i) if (row0 >= padOff[i]) e = i;

    __shared__ unsigned short As[64][40];
    __shared__ unsigned short Bs[64][40];

    const int tid = threadIdx.x;
    const int srow = tid >> 2;
    const int skp = (tid & 3) << 3;

    const unsigned short* aSrc = h + (size_t)(row0 + srow) * FDIM + skp;
    const int dRow = blockIdx.x * 64 + srow;
    const float* bSrc = W2 + ((size_t)e * DDIM + dRow) * FDIM + skp;

    const int lane = tid & 63;
    const int wm = ((tid >> 7) & 1) * 32;
    const int wn = ((tid >> 6) & 1) * 32;
    const int fr = lane & 15;
    const int kg = lane >> 4;

    f32x4 acc[2][2] = {{{0,0,0,0},{0,0,0,0}},{{0,0,0,0},{0,0,0,0}}};

    for (int k0 = 0; k0 < FDIM; k0 += 32) {
        const uint4 av = *(const uint4*)(aSrc + k0);
        const float4 bl = *(const float4*)(bSrc + k0);
        const float4 bh = *(const float4*)(bSrc + k0 + 4);
        uint4 bv;
        bv.x = pk2(bl.x, bl.y); bv.y = pk2(bl.z, bl.w);
        bv.z = pk2(bh.x, bh.y); bv.w = pk2(bh.z, bh.w);

        __syncthreads();
        *(uint4*)&As[srow][skp] = av;
        *(uint4*)&Bs[srow][skp] = bv;
        __syncthreads();

        const bf16x8 a0 = *(const bf16x8*)&As[wm + 0  + fr][kg << 3];
        const bf16x8 a1 = *(const bf16x8*)&As[wm + 16 + fr][kg << 3];
        const bf16x8 b0 = *(const bf16x8*)&Bs[wn + 0  + fr][kg << 3];
        const bf16x8 b1v = *(const bf16x8*)&Bs[wn + 16 + fr][kg << 3];
        acc[0][0] = __builtin_amdgcn_mfma_f32_16x16x32_bf16(a0, b0,  acc[0][0], 0, 0, 0);
        acc[0][1] = __builtin_amdgcn_mfma_f32_16x16x32_bf16(a0, b1v, acc[0][1], 0, 0, 0);
        acc[1][0] = __builtin_amdgcn_mfma_f32_16x16x32_bf16(a1, b0,  acc[1][0], 0, 0, 0);
        acc[1][1] = __builtin_amdgcn_mfma_f32_16x16x32_bf16(a1, b1v, acc[1][1], 0, 0, 0);
    }

#pragma unroll
    for (int mi = 0; mi < 2; ++mi)
#pragma unroll
        for (int ni = 0; ni < 2; ++ni) {
            const int colg = blockIdx.x * 64 + wn + ni * 16 + fr;
            const float bias = b2[e * DDIM + colg];
#pragma unroll
            for (int r = 0; r < 4; ++r) {
                const int rowg = row0 + wm + mi * 16 + (kg << 2) + r;
                const int pm = perm[rowg];
                if (pm >= 0) {
                    const float w = weight[pm];
                    const float v = (acc[mi][ni][r] + bias) * w;
                    atomicAdd(&out[(size_t)(pm >> 1) * DDIM + colg], v);
                }
            }
        }
}

extern "C" void kernel_launch(void* const* d_in, const int* in_sizes, int n_in,
                              void* d_out, int out_size, void* d_ws, size_t ws_size,
                              hipStream_t stream)
{
    const float* x  = (const float*)d_in[0];
    const float* Wr = (const float*)d_in[1];
    const float* W1 = (const float*)d_in[2];
    const float* b1 = (const float*)d_in[3];
    const float* W2 = (const float*)d_in[4];
    const float* b2 = (const float*)d_in[5];
    float* out = (float*)d_out;
    char* ws = (char*)d_ws;

    float* topk_vals = (float*)(ws);                  // 32KB
    float* weight    = (float*)(ws + 32768);          // 32KB
    int*   topk_idx  = (int*)(ws + 65536);            // 32KB
    int*   counts    = (int*)(ws + 98304);
    int*   padOff    = (int*)(ws + 98368);
    int*   cursor    = (int*)(ws + 98432);
    int*   perm      = (int*)(ws + 98496);            // 9216 ints -> ends 135360

    // proven-available layout (r5/r7 ran with this exact gate)
    const size_t NEED = 159645696ULL;

    if (ws_size >= NEED) {
        unsigned short* Xb = (unsigned short*)(ws + 262144);     // 8.39 MB
        unsigned short* h  = (unsigned short*)(ws + 8650752);    // up to 83.9 MB region
        unsigned short* Wb = (unsigned short*)(ws + 92536832);   // 67.1 MB -> ends 159645696

        hipMemsetAsync(counts, 0, NEXP * sizeof(int), stream);
        hipMemsetAsync(perm, 0xFF, N_MAXROWS * sizeof(int), stream);
        hipMemsetAsync(out, 0, (size_t)out_size * sizeof(float), stream);

        cvt_kernel<<<2048, 256, 0, stream>>>(x, Xb, NTOK * DDIM / 4);
        cvt_kernel<<<2048, 256, 0, stream>>>(W1, Wb, NEXP * FDIM * DDIM / 4);
        router_kernel<<<NTOK / 4, 256, 0, stream>>>(x, Wr, topk_vals, topk_idx, counts);
        softmax_seq_kernel<<<4, 256, 0, stream>>>(topk_vals, weight);
        scan_kernel<<<1, 64, 0, stream>>>(counts, padOff, cursor, 7);
        scatter_kernel<<<NTOK / 256, 256, 0, stream>>>(topk_idx, padOff, cursor, perm);

        gemm1_s<<<32 * N_MT, 256, 0, stream>>>(Xb, Wb, b1, perm, padOff, h);
        // W2 conversion reuses Wb (stream-ordered after gemm1 finished with W1b)
        cvt_kernel<<<2048, 256, 0, stream>>>(W2, Wb, NEXP * DDIM * FDIM / 4);
        gemm2_s<<<16 * N_MT, 256, 0, stream>>>(h, Wb, b2, perm, padOff, weight, out);
    } else {
        unsigned short* h = (unsigned short*)(ws + 172032);

        hipMemsetAsync(counts, 0, NEXP * sizeof(int), stream);
        hipMemsetAsync(perm, 0xFF, FB_MAXROWS * sizeof(int), stream);
        hipMemsetAsync(out, 0, (size_t)out_size * sizeof(float), stream);

        router_kernel<<<NTOK / 4, 256, 0, stream>>>(x, Wr, topk_vals, topk_idx, counts);
        softmax_seq_kernel<<<4, 256, 0, stream>>>(topk_vals, weight);
        scan_kernel<<<1, 64, 0, stream>>>(counts, padOff, cursor, 6);
        scatter_kernel<<<NTOK / 256, 256, 0, stream>>>(topk_idx, padOff, cursor, perm);

        gemm1_fb<<<dim3(FDIM / 64, FB_MAXTILES), 256, 0, stream>>>(x, W1, b1, perm, padOff, h);
        gemm2_fb<<<dim3(DDIM / 64, FB_MAXTILES), 256, 0, stream>>>(h, W2, b2, perm, padOff, weight, out);
    }
}